// Round 4
// baseline (63.290 us; speedup 1.0000x reference)
//
#include <hip/hip_runtime.h>

// RayTracing: B=4, P=32768 rays, analytic sphere SDF.
// Two-phase compaction:
//   k0: zero worklist counter (d_ws is not re-poisoned between replays)
//   k1: sphere trace, 2 lanes/ray; writes trace-based outputs for ALL rays;
//       appends unconverged (sampler) rays to a worklist in d_ws
//   k2: dense march + secant ONLY for worklist rays (4 lanes/ray), overwrites
//       their 5 outputs. Formulas bit-identical to the R3 single-kernel path.
// Fallback: single R3-style kernel if ws_size is too small.

#define SDF_THR   5e-05f
#define NSTEPS    100
#define NSECANT   8
#define NTRACE    10

__device__ __forceinline__ float fsqrt(float x) {
    float r; asm("v_sqrt_f32 %0, %1" : "=v"(r) : "v"(x)); return r;
}
__device__ __forceinline__ float frcp(float x) {
    float r; asm("v_rcp_f32 %0, %1" : "=v"(r) : "v"(x)); return r;
}

// ---------------- kernel 0: zero the worklist counter ----------------
__global__ void zero_counter_kernel(unsigned* __restrict__ cnt) {
    if (threadIdx.x == 0 && blockIdx.x == 0) cnt[0] = 0;
}

// ---------------- kernel 1: sphere trace + compaction ----------------
__global__ __launch_bounds__(256) void trace_kernel(
    const float* __restrict__ cam_loc,     // [B,3]
    const float* __restrict__ ray_dirs,    // [B,P,3]
    const float* __restrict__ sdf_center,  // [3]
    const float* __restrict__ sdf_radius,  // [1]
    float* __restrict__ out,               // [3N pts | N mask | N dist]
    unsigned* __restrict__ wcount,
    unsigned* __restrict__ widx,
    float2* __restrict__ wmm,
    int n_total)
{
    int t = blockIdx.x * blockDim.x + threadIdx.x;
    int n = t >> 1;                 // ray index
    int h = t & 1;                  // 0 = start end, 1 = far end
    if (n >= n_total) return;
    int b = n >> 15;                // n / P, P = 32768

    const float dx = ray_dirs[3*n+0], dy = ray_dirs[3*n+1], dz = ray_dirs[3*n+2];
    const float cx = cam_loc[3*b+0], cy = cam_loc[3*b+1], cz = cam_loc[3*b+2];
    const float scx = sdf_center[0], scy = sdf_center[1], scz = sdf_center[2];
    const float rad = sdf_radius[0];

    // quadratic coeffs of squared distance along ray (+1e-12 folded in)
    const float ex = cx - scx, ey = cy - scy, ez = cz - scz;
    const float dd  = dx*dx + dy*dy + dz*dz;
    const float de2 = 2.0f * (dx*ex + dy*ey + dz*ez);
    const float ee1 = (ex*ex + ey*ey + ez*ez) + 1e-12f;

    // ---- bounding-sphere intersection (R=1) ----
    float rcd  = dx*cx + dy*cy + dz*cz;
    float cam2 = cx*cx + cy*cy + cz*cz;
    float under = rcd*rcd - (cam2 - 1.0f);
    bool mask_int = under > 0.0f;
    float sq = fsqrt(mask_int ? under : 0.0f);
    float si0 = fmaxf(mask_int ? (-sq - rcd) : 0.0f, 0.0f);
    float si1 = fmaxf(mask_int ? ( sq - rcd) : 0.0f, 0.0f);

    // ---- sphere tracing: this lane owns one end ----
    float my_acc = h ? si1 : si0;
    const float sgn = h ? -1.0f : 1.0f;     // s end adds, e end subtracts
    bool my_unfin = mask_int;
    float next;
    {
        float u0 = fmaf(my_acc, fmaf(my_acc, dd, de2), ee1);
        next = my_unfin ? (fsqrt(u0) - rad) : 0.0f;
    }

    float acc_s = my_acc, acc_e = my_acc;
    #pragma unroll
    for (int it = 0; it < NTRACE; ++it) {
        float curr = my_unfin ? next : 0.0f;
        curr = (curr <= SDF_THR) ? 0.0f : curr;
        my_unfin = my_unfin && (curr > SDF_THR);
        my_acc = fmaf(sgn, curr, my_acc);
        float u = fmaf(my_acc, fmaf(my_acc, dd, de2), ee1);
        next = my_unfin ? (fsqrt(u) - rad) : 0.0f;
        // line-search back-off: exact SDF -> essentially never taken
        if (next < 0.0f) {
            my_acc = fmaf(-sgn, 0.5f * curr, my_acc);
            float u2 = fmaf(my_acc, fmaf(my_acc, dd, de2), ee1);
            next = fsqrt(u2) - rad;
        }
        float pacc = __shfl_xor(my_acc, 1);
        acc_s = h ? pacc : my_acc;
        acc_e = h ? my_acc : pacc;
        bool ok = acc_s < acc_e;
        my_unfin = my_unfin && ok;
    }
    // final mask refresh (only the s-lane's value is used)
    bool sampler_s = my_unfin;
    {
        float curr = my_unfin ? next : 0.0f;
        curr = (curr <= SDF_THR) ? 0.0f : curr;
        sampler_s = my_unfin && (curr > SDF_THR);
    }
    const bool netmask_trace = acc_s < acc_e;

    // trace-based outputs for every ray (kernel 2 overwrites sampler rays)
    if (h == 0) {
        out[3*n + 0] = fmaf(acc_s, dx, cx);
        out[3*n + 1] = fmaf(acc_s, dy, cy);
        out[3*n + 2] = fmaf(acc_s, dz, cz);
    } else {
        out[3*n_total + n] = netmask_trace ? 1.0f : 0.0f;
        out[4*n_total + n] = acc_s;
    }

    // ---- wave-aggregated worklist append (h==0 lanes only) ----
    bool want = (h == 0) && sampler_s;
    unsigned long long m = __ballot(want);
    if (m != 0ULL) {
        int lane = threadIdx.x & 63;
        int leader = __ffsll((unsigned long long)m) - 1;
        unsigned base = 0;
        if (lane == leader) base = atomicAdd(wcount, (unsigned)__popcll(m));
        base = (unsigned)__shfl((int)base, leader);
        if (want) {
            unsigned pos = base + (unsigned)__popcll(m & ((1ULL << lane) - 1ULL));
            widx[pos] = (unsigned)n;
            wmm[pos]  = make_float2(acc_s, acc_e);
        }
    }
}

// ---------------- kernel 2: dense march + secant for sampler rays ----------------
__global__ __launch_bounds__(256) void march_kernel(
    const float* __restrict__ cam_loc,
    const float* __restrict__ ray_dirs,
    const float* __restrict__ sdf_center,
    const float* __restrict__ sdf_radius,
    float* __restrict__ out,
    const unsigned* __restrict__ wcount,
    const unsigned* __restrict__ widx,
    const float2* __restrict__ wmm,
    int n_total)
{
    int t = blockIdx.x * blockDim.x + threadIdx.x;
    int slot = t >> 2;              // worklist slot
    int q = t & 3;                  // 4 lanes per sampler ray
    unsigned count = wcount[0];
    if ((unsigned)slot >= count) return;

    int n = (int)widx[slot];
    float2 mm = wmm[slot];
    float smin = mm.x, smax = mm.y;
    int b = n >> 15;

    const float dx = ray_dirs[3*n+0], dy = ray_dirs[3*n+1], dz = ray_dirs[3*n+2];
    const float cx = cam_loc[3*b+0], cy = cam_loc[3*b+1], cz = cam_loc[3*b+2];
    const float scx = sdf_center[0], scy = sdf_center[1], scz = sdf_center[2];
    const float rad = sdf_radius[0];

    const float ex = cx - scx, ey = cy - scy, ez = cz - scz;
    const float dd  = dx*dx + dy*dy + dz*dz;
    const float de2 = 2.0f * (dx*ex + dy*ey + dz*ez);
    const float ee1 = (ex*ex + ey*ey + ez*ez) + 1e-12f;

    float sz = (smax - smin) * (1.0f / 99.0f);   // z_i = fma(i, sz, smin)

    // v_sqrt-consistent thresholds: fsqrt(u) < rad  <=> u <= u_neg_max
    //                                fsqrt(u) <= rad <=> u <= u_le_max
    float r2 = rad * rad;
    unsigned rb = __float_as_uint(r2);
    float u_neg_max = __uint_as_float(rb - 7u);
    float u_le_max  = u_neg_max;
    #pragma unroll
    for (int k = -6; k <= 6; ++k) {
        float u = __uint_as_float(rb + (unsigned)k);
        float v = fsqrt(u);
        if (v <  rad) u_neg_max = u;   // ascending: last wins = max
        if (v <= rad) u_le_max  = u;
    }

    // strided first-(sdf<=0) scan: lane q covers i = q, q+4, ...
    float kmf = 1e30f;
    float i_f = (float)q;
    #pragma unroll
    for (int s = 0; s < NSTEPS / 4; ++s) {
        float z = fmaf(i_f, sz, smin);
        float u = fmaf(z, fmaf(z, dd, de2), ee1);
        kmf = fminf(kmf, (u <= u_le_max) ? i_f : 1e30f);
        i_f += 4.0f;
    }
    kmf = fminf(kmf, __shfl_xor(kmf, 1));
    kmf = fminf(kmf, __shfl_xor(kmf, 2));

    bool net_surface = false;
    int ind;
    if (kmf < 1e29f) {
        int km = (int)kmf;
        float zk = fmaf(kmf, sz, smin);
        float uk = fmaf(zk, fmaf(zk, dd, de2), ee1);
        if (uk <= u_neg_max) {
            ind = km; net_surface = true;      // first crossing is negative
        } else {
            // exact-tie (sdf==0) at km: reference prefers first NEGATIVE
            ind = km; net_surface = false;
            for (int i = km + 1; i < NSTEPS; ++i) {
                float z = fmaf((float)i, sz, smin);
                float u = fmaf(z, fmaf(z, dd, de2), ee1);
                if (u <= u_neg_max) { ind = i; net_surface = true; break; }
            }
        }
    } else {
        ind = NSTEPS - 1; net_surface = false;
    }
    int indm1 = (ind == 0) ? (NSTEPS - 1) : (ind - 1);   // python -1 wrap

    float z_high = fmaf((float)ind,   sz, smin);
    float z_low  = fmaf((float)indm1, sz, smin);
    float zh_out = z_high;                    // reference outputs z[ind]
    float uh = fmaf(z_high, fmaf(z_high, dd, de2), ee1);
    float ul = fmaf(z_low,  fmaf(z_low,  dd, de2), ee1);
    float sdf_high = fsqrt(uh) - rad;
    float sdf_low  = fsqrt(ul) - rad;
    float pix = fmaf(z_high, dx, cx);
    float piy = fmaf(z_high, dy, cy);
    float piz = fmaf(z_high, dz, cz);

    // ---- secant root finding ----
    float den = sdf_high - sdf_low;
    float dinv = frcp((den == 0.0f) ? 1.0f : den);
    float z_pred = fmaf(-sdf_low, (z_high - z_low) * dinv, z_low);
    #pragma unroll
    for (int i = 0; i < NSECANT; ++i) {
        float um = fmaf(z_pred, fmaf(z_pred, dd, de2), ee1);
        float sm = fsqrt(um) - rad;
        if (sm > 0.0f) { z_low  = z_pred; sdf_low  = sm; }
        if (sm < 0.0f) { z_high = z_pred; sdf_high = sm; }
        den = sdf_high - sdf_low;
        dinv = frcp((den == 0.0f) ? 1.0f : den);
        z_pred = fmaf(-sdf_low, (z_high - z_low) * dinv, z_low);
    }

    // ---- outputs for this sampler ray ----
    float ox, oy, oz, odis;
    if (net_surface) {
        ox = fmaf(z_pred, dx, cx);
        oy = fmaf(z_pred, dy, cy);
        oz = fmaf(z_pred, dz, cz);
        odis = z_pred;
    } else {
        ox = pix; oy = piy; oz = piz;
        odis = zh_out;
    }
    if (q == 0) {
        out[3*n + 0] = ox;
        out[3*n + 1] = oy;
        out[3*n + 2] = oz;
    } else if (q == 1) {
        out[3*n_total + n] = net_surface ? 1.0f : 0.0f;
    } else if (q == 2) {
        out[4*n_total + n] = odis;
    }
}

// ---------------- fallback: R3 single-kernel path ----------------
__global__ __launch_bounds__(256) void fallback_kernel(
    const float* __restrict__ cam_loc, const float* __restrict__ ray_dirs,
    const float* __restrict__ sdf_center, const float* __restrict__ sdf_radius,
    float* __restrict__ out, int n_total)
{
    int t = blockIdx.x * blockDim.x + threadIdx.x;
    int n = t >> 1, h = t & 1;
    if (n >= n_total) return;
    int b = n >> 15;

    const float dx = ray_dirs[3*n+0], dy = ray_dirs[3*n+1], dz = ray_dirs[3*n+2];
    const float cx = cam_loc[3*b+0], cy = cam_loc[3*b+1], cz = cam_loc[3*b+2];
    const float scx = sdf_center[0], scy = sdf_center[1], scz = sdf_center[2];
    const float rad = sdf_radius[0];

    const float ex = cx - scx, ey = cy - scy, ez = cz - scz;
    const float dd  = dx*dx + dy*dy + dz*dz;
    const float de2 = 2.0f * (dx*ex + dy*ey + dz*ez);
    const float ee1 = (ex*ex + ey*ey + ez*ez) + 1e-12f;

    float rcd  = dx*cx + dy*cy + dz*cz;
    float cam2 = cx*cx + cy*cy + cz*cz;
    float under = rcd*rcd - (cam2 - 1.0f);
    bool mask_int = under > 0.0f;
    float sq = fsqrt(mask_int ? under : 0.0f);
    float si0 = fmaxf(mask_int ? (-sq - rcd) : 0.0f, 0.0f);
    float si1 = fmaxf(mask_int ? ( sq - rcd) : 0.0f, 0.0f);

    float my_acc = h ? si1 : si0;
    const float sgn = h ? -1.0f : 1.0f;
    bool my_unfin = mask_int;
    float next;
    {
        float u0 = fmaf(my_acc, fmaf(my_acc, dd, de2), ee1);
        next = my_unfin ? (fsqrt(u0) - rad) : 0.0f;
    }
    float acc_s = my_acc, acc_e = my_acc;
    #pragma unroll
    for (int it = 0; it < NTRACE; ++it) {
        float curr = my_unfin ? next : 0.0f;
        curr = (curr <= SDF_THR) ? 0.0f : curr;
        my_unfin = my_unfin && (curr > SDF_THR);
        my_acc = fmaf(sgn, curr, my_acc);
        float u = fmaf(my_acc, fmaf(my_acc, dd, de2), ee1);
        next = my_unfin ? (fsqrt(u) - rad) : 0.0f;
        if (next < 0.0f) {
            my_acc = fmaf(-sgn, 0.5f * curr, my_acc);
            float u2 = fmaf(my_acc, fmaf(my_acc, dd, de2), ee1);
            next = fsqrt(u2) - rad;
        }
        float pacc = __shfl_xor(my_acc, 1);
        acc_s = h ? pacc : my_acc;
        acc_e = h ? my_acc : pacc;
        bool ok = acc_s < acc_e;
        my_unfin = my_unfin && ok;
    }
    bool unfin_s_f = my_unfin;
    {
        float curr = my_unfin ? next : 0.0f;
        curr = (curr <= SDF_THR) ? 0.0f : curr;
        unfin_s_f = my_unfin && (curr > SDF_THR);
    }
    int smi = __shfl_xor(h ? 0 : (int)unfin_s_f, 1);
    const bool sampler = h ? (smi != 0) : unfin_s_f;
    const bool netmask_trace = acc_s < acc_e;

    bool net_surface = false;
    float z_pred = 0.0f, zh_out = 0.0f;
    float pix = 0.0f, piy = 0.0f, piz = 0.0f;

    if (__ballot(sampler) != 0ULL) {
        float smin = sampler ? acc_s : 0.0f;
        float smax = sampler ? acc_e : 0.0f;
        float sz = (smax - smin) * (1.0f / 99.0f);

        float r2 = rad * rad;
        unsigned rb = __float_as_uint(r2);
        float u_neg_max = __uint_as_float(rb - 7u);
        float u_le_max  = u_neg_max;
        #pragma unroll
        for (int k = -6; k <= 6; ++k) {
            float u = __uint_as_float(rb + (unsigned)k);
            float v = fsqrt(u);
            if (v <  rad) u_neg_max = u;
            if (v <= rad) u_le_max  = u;
        }

        float kmf = 1e30f;
        float i_f = (float)h;
        #pragma unroll
        for (int s = 0; s < NSTEPS / 2; ++s) {
            float z = fmaf(i_f, sz, smin);
            float u = fmaf(z, fmaf(z, dd, de2), ee1);
            kmf = fminf(kmf, (u <= u_le_max) ? i_f : 1e30f);
            i_f += 2.0f;
        }
        kmf = fminf(kmf, __shfl_xor(kmf, 1));

        int ind;
        if (kmf < 1e29f) {
            int km = (int)kmf;
            float zk = fmaf(kmf, sz, smin);
            float uk = fmaf(zk, fmaf(zk, dd, de2), ee1);
            if (uk <= u_neg_max) { ind = km; net_surface = true; }
            else {
                ind = km; net_surface = false;
                for (int i = km + 1; i < NSTEPS; ++i) {
                    float z = fmaf((float)i, sz, smin);
                    float u = fmaf(z, fmaf(z, dd, de2), ee1);
                    if (u <= u_neg_max) { ind = i; net_surface = true; break; }
                }
            }
        } else { ind = NSTEPS - 1; net_surface = false; }
        int indm1 = (ind == 0) ? (NSTEPS - 1) : (ind - 1);

        float z_high = fmaf((float)ind,   sz, smin);
        float z_low  = fmaf((float)indm1, sz, smin);
        zh_out = z_high;
        float uh = fmaf(z_high, fmaf(z_high, dd, de2), ee1);
        float ul = fmaf(z_low,  fmaf(z_low,  dd, de2), ee1);
        float sdf_high = fsqrt(uh) - rad;
        float sdf_low  = fsqrt(ul) - rad;
        pix = fmaf(z_high, dx, cx);
        piy = fmaf(z_high, dy, cy);
        piz = fmaf(z_high, dz, cz);

        float den = sdf_high - sdf_low;
        float dinv = frcp((den == 0.0f) ? 1.0f : den);
        z_pred = fmaf(-sdf_low, (z_high - z_low) * dinv, z_low);
        #pragma unroll
        for (int i = 0; i < NSECANT; ++i) {
            float um = fmaf(z_pred, fmaf(z_pred, dd, de2), ee1);
            float sm = fsqrt(um) - rad;
            if (sm > 0.0f) { z_low  = z_pred; sdf_low  = sm; }
            if (sm < 0.0f) { z_high = z_pred; sdf_high = sm; }
            den = sdf_high - sdf_low;
            dinv = frcp((den == 0.0f) ? 1.0f : den);
            z_pred = fmaf(-sdf_low, (z_high - z_low) * dinv, z_low);
        }
    }

    float ox, oy, oz, odis;
    bool omask;
    if (sampler) {
        if (net_surface) {
            ox = fmaf(z_pred, dx, cx);
            oy = fmaf(z_pred, dy, cy);
            oz = fmaf(z_pred, dz, cz);
            odis = z_pred;
        } else { ox = pix; oy = piy; oz = piz; odis = zh_out; }
        omask = net_surface;
    } else {
        ox = fmaf(acc_s, dx, cx);
        oy = fmaf(acc_s, dy, cy);
        oz = fmaf(acc_s, dz, cz);
        odis = acc_s;
        omask = netmask_trace;
    }

    if (h == 0) {
        out[3*n + 0] = ox; out[3*n + 1] = oy; out[3*n + 2] = oz;
    } else {
        out[3*n_total + n] = omask ? 1.0f : 0.0f;
        out[4*n_total + n] = odis;
    }
}

extern "C" void kernel_launch(void* const* d_in, const int* in_sizes, int n_in,
                              void* d_out, int out_size, void* d_ws, size_t ws_size,
                              hipStream_t stream) {
    const float* cam_loc    = (const float*)d_in[0];
    const float* ray_dirs   = (const float*)d_in[1];
    // d_in[2] = object_mask (unused in eval-mode forward)
    const float* sdf_center = (const float*)d_in[3];
    const float* sdf_radius = (const float*)d_in[4];
    float* out = (float*)d_out;

    int n_total = in_sizes[1] / 3;   // B*P rays

    size_t idx_off = 16;
    size_t mm_off  = (idx_off + 4u * (size_t)n_total + 7u) & ~(size_t)7u;
    size_t need    = mm_off + 8u * (size_t)n_total;

    if (ws_size >= need) {
        unsigned* wcount = (unsigned*)d_ws;
        unsigned* widx   = (unsigned*)((char*)d_ws + idx_off);
        float2*   wmm    = (float2*)((char*)d_ws + mm_off);

        zero_counter_kernel<<<1, 64, 0, stream>>>(wcount);

        int threads1 = 2 * n_total;
        trace_kernel<<<(threads1 + 255) / 256, 256, 0, stream>>>(
            cam_loc, ray_dirs, sdf_center, sdf_radius, out,
            wcount, widx, wmm, n_total);

        int threads2 = 4 * n_total;
        march_kernel<<<(threads2 + 255) / 256, 256, 0, stream>>>(
            cam_loc, ray_dirs, sdf_center, sdf_radius, out,
            wcount, widx, wmm, n_total);
    } else {
        int threads = 2 * n_total;
        fallback_kernel<<<(threads + 255) / 256, 256, 0, stream>>>(
            cam_loc, ray_dirs, sdf_center, sdf_radius, out, n_total);
    }
}

// Round 5
// 16.326 us; speedup vs baseline: 3.8767x; 3.8767x over previous
//
#include <hip/hip_runtime.h>

// RayTracing: B=4, P=32768 rays, analytic sphere SDF.
// Single kernel, 2 lanes/ray trace + BLOCK-LOCAL LDS compaction + cooperative
// march (4 lanes/compacted ray). No global atomics (R4's 52us stall was
// same-address device-scope atomicAdd serialization across 4096 waves).
// All SDF evals use the per-ray quadratic u(z) = dd z^2 + de2 z + (ee+1e-12),
// with sqrt-free sign classification against v_sqrt-consistent thresholds.

#define SDF_THR   5e-05f
#define NSTEPS    100
#define NSECANT   8
#define NTRACE    10

__device__ __forceinline__ float fsqrt(float x) {
    float r; asm("v_sqrt_f32 %0, %1" : "=v"(r) : "v"(x)); return r;
}
__device__ __forceinline__ float frcp(float x) {
    float r; asm("v_rcp_f32 %0, %1" : "=v"(r) : "v"(x)); return r;
}

__global__ __launch_bounds__(256) void ray_kernel(
    const float* __restrict__ cam_loc,     // [B,3]
    const float* __restrict__ ray_dirs,    // [B,P,3]
    const float* __restrict__ sdf_center,  // [3]
    const float* __restrict__ sdf_radius,  // [1]
    float* __restrict__ out,               // [3N pts | N mask | N dist]
    int n_total)
{
    __shared__ unsigned short s_idx[128];  // local ray index of sampler rays
    __shared__ float2         s_mm[128];   // their (acc_s, acc_e)
    __shared__ unsigned       s_wcnt[4];   // per-wave sampler counts

    const int t = blockIdx.x * blockDim.x + threadIdx.x;
    const int n = t >> 1;                  // ray index
    const int h = t & 1;                   // 0 = start end, 1 = far end
    const bool valid = (n < n_total);
    const int nc = valid ? n : 0;
    const int b = nc >> 15;                // n / P, P = 32768

    const float dx = ray_dirs[3*nc+0], dy = ray_dirs[3*nc+1], dz = ray_dirs[3*nc+2];
    const float cx = cam_loc[3*b+0], cy = cam_loc[3*b+1], cz = cam_loc[3*b+2];
    const float scx = sdf_center[0], scy = sdf_center[1], scz = sdf_center[2];
    const float rad = sdf_radius[0];

    // quadratic coeffs of squared distance along ray (+1e-12 folded in)
    const float ex = cx - scx, ey = cy - scy, ez = cz - scz;
    const float dd  = dx*dx + dy*dy + dz*dz;
    const float de2 = 2.0f * (dx*ex + dy*ey + dz*ez);
    const float ee1 = (ex*ex + ey*ey + ez*ez) + 1e-12f;

    // ---- bounding-sphere intersection (R=1) ----
    float rcd  = dx*cx + dy*cy + dz*cz;
    float cam2 = cx*cx + cy*cy + cz*cz;
    float under = rcd*rcd - (cam2 - 1.0f);
    bool mask_int = valid && (under > 0.0f);
    float sq = fsqrt(mask_int ? under : 0.0f);
    float si0 = fmaxf(mask_int ? (-sq - rcd) : 0.0f, 0.0f);
    float si1 = fmaxf(mask_int ? ( sq - rcd) : 0.0f, 0.0f);

    // ---- sphere tracing: this lane owns one end ----
    float my_acc = h ? si1 : si0;
    const float sgn = h ? -1.0f : 1.0f;     // s end adds, e end subtracts
    bool my_unfin = mask_int;
    float next;
    {
        float u0 = fmaf(my_acc, fmaf(my_acc, dd, de2), ee1);
        next = my_unfin ? (fsqrt(u0) - rad) : 0.0f;
    }

    float acc_s = my_acc, acc_e = my_acc;
    #pragma unroll
    for (int it = 0; it < NTRACE; ++it) {
        float curr = my_unfin ? next : 0.0f;
        curr = (curr <= SDF_THR) ? 0.0f : curr;
        my_unfin = my_unfin && (curr > SDF_THR);
        my_acc = fmaf(sgn, curr, my_acc);
        float u = fmaf(my_acc, fmaf(my_acc, dd, de2), ee1);
        next = my_unfin ? (fsqrt(u) - rad) : 0.0f;
        // line-search back-off: exact SDF -> essentially never taken
        if (next < 0.0f) {
            my_acc = fmaf(-sgn, 0.5f * curr, my_acc);
            float u2 = fmaf(my_acc, fmaf(my_acc, dd, de2), ee1);
            next = fsqrt(u2) - rad;
        }
        float pacc = __shfl_xor(my_acc, 1);
        acc_s = h ? pacc : my_acc;
        acc_e = h ? my_acc : pacc;
        bool ok = acc_s < acc_e;
        my_unfin = my_unfin && ok;
    }
    // final mask refresh (only the s-lane's value matters for the ray)
    bool sampler_s = my_unfin;
    {
        float curr = my_unfin ? next : 0.0f;
        curr = (curr <= SDF_THR) ? 0.0f : curr;
        sampler_s = my_unfin && (curr > SDF_THR);
    }
    const bool netmask_trace = acc_s < acc_e;

    // ray-level sampler flag on both lanes
    int smi = __shfl_xor(h ? 0 : (int)sampler_s, 1);
    const bool sampler = h ? (smi != 0) : sampler_s;

    // trace-based outputs for NON-sampler rays only (march writes the rest;
    // disjoint addresses -> no ordering hazard)
    if (valid && !sampler) {
        if (h == 0) {
            out[3*n + 0] = fmaf(acc_s, dx, cx);
            out[3*n + 1] = fmaf(acc_s, dy, cy);
            out[3*n + 2] = fmaf(acc_s, dz, cz);
        } else {
            out[3*n_total + n] = netmask_trace ? 1.0f : 0.0f;
            out[4*n_total + n] = acc_s;
        }
    }

    // ---- block-local compaction of sampler rays (no global atomics) ----
    bool want = valid && (h == 0) && sampler_s;
    unsigned long long m = __ballot(want);
    const int wid  = threadIdx.x >> 6;
    const int lane = threadIdx.x & 63;
    if (lane == 0) s_wcnt[wid] = (unsigned)__popcll(m);
    __syncthreads();
    unsigned base = 0;
    #pragma unroll
    for (int w = 0; w < 3; ++w) if (w < wid) base += s_wcnt[w];
    const unsigned total = s_wcnt[0] + s_wcnt[1] + s_wcnt[2] + s_wcnt[3];
    if (want) {
        unsigned pos = base + (unsigned)__popcll(m & ((1ULL << lane) - 1ULL));
        s_idx[pos] = (unsigned short)(threadIdx.x >> 1);  // local ray 0..127
        s_mm[pos]  = make_float2(acc_s, acc_e);
    }
    __syncthreads();

    if (total == 0) return;   // uniform across block

    // ---- cooperative dense march + secant over the compacted list ----
    // v_sqrt-consistent thresholds: fsqrt(u) < rad  <=> u <= u_neg_max
    //                                fsqrt(u) <= rad <=> u <= u_le_max
    float r2 = rad * rad;
    unsigned rb = __float_as_uint(r2);
    float u_neg_max = __uint_as_float(rb - 7u);
    float u_le_max  = u_neg_max;
    #pragma unroll
    for (int k = -6; k <= 6; ++k) {
        float u = __uint_as_float(rb + (unsigned)k);
        float v = fsqrt(u);
        if (v <  rad) u_neg_max = u;   // ascending: last wins = max
        if (v <= rad) u_le_max  = u;
    }

    const int slot0 = threadIdx.x >> 2;    // 64 slots per pass
    const int q = threadIdx.x & 3;         // 4 lanes per sampler ray
    const int ray_base = (blockIdx.x * blockDim.x) >> 1;  // block's first ray

    for (unsigned slot = (unsigned)slot0; slot < total; slot += 64) {
        const int r = (int)s_idx[slot];            // broadcast read
        const float2 mm = s_mm[slot];
        const float smin = mm.x, smax = mm.y;
        const int nn = ray_base + r;
        const int bb = nn >> 15;

        const float rdx = ray_dirs[3*nn+0], rdy = ray_dirs[3*nn+1], rdz = ray_dirs[3*nn+2];
        const float rcx = cam_loc[3*bb+0], rcy = cam_loc[3*bb+1], rcz = cam_loc[3*bb+2];
        const float rex = rcx - scx, rey = rcy - scy, rez = rcz - scz;
        const float rdd  = rdx*rdx + rdy*rdy + rdz*rdz;
        const float rde2 = 2.0f * (rdx*rex + rdy*rey + rdz*rez);
        const float ree1 = (rex*rex + rey*rey + rez*rez) + 1e-12f;

        const float sz = (smax - smin) * (1.0f / 99.0f);  // z_i = fma(i,sz,smin)

        // strided first-(sdf<=0) scan: lane q covers i = q, q+4, ...
        float kmf = 1e30f;
        float i_f = (float)q;
        #pragma unroll
        for (int s = 0; s < NSTEPS / 4; ++s) {
            float z = fmaf(i_f, sz, smin);
            float u = fmaf(z, fmaf(z, rdd, rde2), ree1);
            kmf = fminf(kmf, (u <= u_le_max) ? i_f : 1e30f);
            i_f += 4.0f;
        }
        kmf = fminf(kmf, __shfl_xor(kmf, 1));   // 4-lane group aligned to 4
        kmf = fminf(kmf, __shfl_xor(kmf, 2));

        bool net_surface = false;
        int ind;
        if (kmf < 1e29f) {
            int km = (int)kmf;
            float zk = fmaf(kmf, sz, smin);
            float uk = fmaf(zk, fmaf(zk, rdd, rde2), ree1);
            if (uk <= u_neg_max) {
                ind = km; net_surface = true;     // first crossing is negative
            } else {
                // exact-tie (sdf==0) at km: reference prefers first NEGATIVE
                ind = km; net_surface = false;
                for (int i = km + 1; i < NSTEPS; ++i) {
                    float z = fmaf((float)i, sz, smin);
                    float u = fmaf(z, fmaf(z, rdd, rde2), ree1);
                    if (u <= u_neg_max) { ind = i; net_surface = true; break; }
                }
            }
        } else {
            ind = NSTEPS - 1; net_surface = false;
        }
        int indm1 = (ind == 0) ? (NSTEPS - 1) : (ind - 1);  // python -1 wrap

        float z_high = fmaf((float)ind,   sz, smin);
        float z_low  = fmaf((float)indm1, sz, smin);
        float zh_out = z_high;                    // reference outputs z[ind]
        float uh = fmaf(z_high, fmaf(z_high, rdd, rde2), ree1);
        float ul = fmaf(z_low,  fmaf(z_low,  rdd, rde2), ree1);
        float sdf_high = fsqrt(uh) - rad;
        float sdf_low  = fsqrt(ul) - rad;
        float pix = fmaf(z_high, rdx, rcx);
        float piy = fmaf(z_high, rdy, rcy);
        float piz = fmaf(z_high, rdz, rcz);

        // ---- secant root finding ----
        float den = sdf_high - sdf_low;
        float dinv = frcp((den == 0.0f) ? 1.0f : den);
        float z_pred = fmaf(-sdf_low, (z_high - z_low) * dinv, z_low);
        #pragma unroll
        for (int i = 0; i < NSECANT; ++i) {
            float um = fmaf(z_pred, fmaf(z_pred, rdd, rde2), ree1);
            float sm = fsqrt(um) - rad;
            if (sm > 0.0f) { z_low  = z_pred; sdf_low  = sm; }
            if (sm < 0.0f) { z_high = z_pred; sdf_high = sm; }
            den = sdf_high - sdf_low;
            dinv = frcp((den == 0.0f) ? 1.0f : den);
            z_pred = fmaf(-sdf_low, (z_high - z_low) * dinv, z_low);
        }

        // ---- outputs for this sampler ray ----
        float ox, oy, oz, odis;
        if (net_surface) {
            ox = fmaf(z_pred, rdx, rcx);
            oy = fmaf(z_pred, rdy, rcy);
            oz = fmaf(z_pred, rdz, rcz);
            odis = z_pred;
        } else {
            ox = pix; oy = piy; oz = piz;
            odis = zh_out;
        }
        if (q == 0) {
            out[3*nn + 0] = ox;
            out[3*nn + 1] = oy;
            out[3*nn + 2] = oz;
        } else if (q == 1) {
            out[3*n_total + nn] = net_surface ? 1.0f : 0.0f;
        } else if (q == 2) {
            out[4*n_total + nn] = odis;
        }
    }
}

extern "C" void kernel_launch(void* const* d_in, const int* in_sizes, int n_in,
                              void* d_out, int out_size, void* d_ws, size_t ws_size,
                              hipStream_t stream) {
    const float* cam_loc    = (const float*)d_in[0];
    const float* ray_dirs   = (const float*)d_in[1];
    // d_in[2] = object_mask (unused in eval-mode forward)
    const float* sdf_center = (const float*)d_in[3];
    const float* sdf_radius = (const float*)d_in[4];
    float* out = (float*)d_out;

    int n_total = in_sizes[1] / 3;   // B*P rays
    int threads = 2 * n_total;       // 2 lanes per ray
    int block = 256;
    int grid = (threads + block - 1) / block;
    ray_kernel<<<grid, block, 0, stream>>>(cam_loc, ray_dirs, sdf_center,
                                           sdf_radius, out, n_total);
}